// Round 1
// baseline (849.182 us; speedup 1.0000x reference)
//
#include <hip/hip_runtime.h>

// out[r, c] = x[r, c] * ( (u[c] >= 0.1f) ? vec[c] / 0.9f : 0.0f )
// N_ROWS = 131072, DEPTH = 1024 (fp32). Pure memory-bound columnwise scale.

constexpr int DEPTH   = 1024;
constexpr int N_ROWS  = 131072;
constexpr int BLOCK   = 256;           // 256 threads * float4 = 1024 cols = one row
constexpr int DEPTH4  = DEPTH / 4;     // 256 float4 per row
constexpr float P_DROP = 0.1f;
constexpr float ONE_MINUS_P = 0.9f;

__global__ __launch_bounds__(BLOCK) void MMDropoutDiagonal_kernel(
    const float4* __restrict__ x,
    const float4* __restrict__ vec4,
    const float4* __restrict__ u4,
    float4* __restrict__ out)
{
    const int tid = threadIdx.x;       // 0..255 -> columns [tid*4, tid*4+4)

    // Per-thread dropout scale, computed once, reused across all rows.
    const float4 v  = vec4[tid];
    const float4 uu = u4[tid];
    float4 s;
    s.x = (uu.x >= P_DROP) ? (v.x / ONE_MINUS_P) : 0.0f;
    s.y = (uu.y >= P_DROP) ? (v.y / ONE_MINUS_P) : 0.0f;
    s.z = (uu.z >= P_DROP) ? (v.z / ONE_MINUS_P) : 0.0f;
    s.w = (uu.w >= P_DROP) ? (v.w / ONE_MINUS_P) : 0.0f;

    // Grid-stride over rows; block b handles rows b, b+gridDim, ...
    for (int row = blockIdx.x; row < N_ROWS; row += gridDim.x) {
        const size_t idx = (size_t)row * DEPTH4 + tid;
        float4 xv = x[idx];
        xv.x *= s.x;
        xv.y *= s.y;
        xv.z *= s.z;
        xv.w *= s.w;
        out[idx] = xv;
    }
}

extern "C" void kernel_launch(void* const* d_in, const int* in_sizes, int n_in,
                              void* d_out, int out_size, void* d_ws, size_t ws_size,
                              hipStream_t stream) {
    const float4* x    = (const float4*)d_in[0];
    const float4* vec4 = (const float4*)d_in[1];
    const float4* u4   = (const float4*)d_in[2];
    float4* out        = (float4*)d_out;

    // 16384 blocks -> 8 rows per block; 4x wave oversubscription on 256 CUs.
    const int grid = 16384;
    MMDropoutDiagonal_kernel<<<grid, BLOCK, 0, stream>>>(x, vec4, u4, out);
}